// Round 10
// baseline (585.710 us; speedup 1.0000x reference)
//
#include <hip/hip_runtime.h>

typedef unsigned int u32;
typedef unsigned short u16;

#define D 128

typedef __attribute__((ext_vector_type(8))) short bf16x8;
typedef __attribute__((ext_vector_type(4))) float f32x4;
#define MFMA16x16(a, b, c) __builtin_amdgcn_mfma_f32_16x16x32_bf16(a, b, c, 0, 0, 0)

__device__ inline float b2f(u32 h) { return __uint_as_float((h & 0xffffu) << 16); }
__device__ inline u16 f2b(float f) {
    u32 u = __float_as_uint(f);
    return (u16)((u + 0x7fffu + ((u >> 16) & 1u)) >> 16);
}
__device__ inline float tanh_fast(float x) {
    x = fminf(fmaxf(x, -15.f), 15.f);
    float e = __expf(2.f * x);
    return (e - 1.f) * __builtin_amdgcn_rcpf(e + 1.f);
}

// Packed gather row: AE[n][256] bf16 = [ Ar(0:128) | emb(128:256) ]  (512 B, pow2)
// Ah lives separately in AH[n][128] (read once per node).

// ===================== bucketed CSR build (no global atomics) =====================
// Buckets of 128 nodes: bucket = node >> 7, local = node & 127.
// hist layout: hist[bucket][block], block-count fixed at 256.

__global__ __launch_bounds__(256) void k_bhist(const int* __restrict__ er_src,
                                               const int* __restrict__ er_dst,
                                               const int* __restrict__ ee_src,
                                               const int* __restrict__ rr_src,
                                               int* __restrict__ histA,
                                               int* __restrict__ histM,
                                               int E_ER, int E_EE, int E_RR, int NBK) {
    __shared__ int hA[1024], hM[1024];
    int tid = threadIdx.x;
    for (int j = tid; j < NBK; j += 256) { hA[j] = 0; hM[j] = 0; }
    __syncthreads();
    int E_T = 2 * E_ER + E_EE + E_RR;
    int stride = gridDim.x * 256;
    for (int e = blockIdx.x * 256 + tid; e < E_T; e += stride) {
        int i = e;
        if (i < E_ER) { atomicAdd(&hA[er_src[i] >> 7], 1); continue; }
        i -= E_ER;
        int key;
        if (i < E_ER) key = er_dst[i];
        else {
            i -= E_ER;
            key = (i < E_EE) ? ee_src[i] : rr_src[i - E_EE];
        }
        atomicAdd(&hM[key >> 7], 1);
    }
    __syncthreads();
    for (int j = tid; j < NBK; j += 256) {
        histA[j * 256 + blockIdx.x] = hA[j];
        histM[j * 256 + blockIdx.x] = hM[j];
    }
}

__global__ void k_scan1_dual(const int* __restrict__ cnt2, int n,
                             int* __restrict__ off_src, int* __restrict__ off_mean,
                             int* __restrict__ bsum, int nbs) {
    __shared__ int sh[256];
    int b = blockIdx.x;
    const int* cnt = cnt2;
    int* out = off_src;
    int* bs = bsum;
    if (b >= nbs) { b -= nbs; cnt = cnt2 + n; out = off_mean; bs = bsum + 256; }
    int t = threadIdx.x;
    int base = b * 1024 + t * 4;
    int v0 = (base < n) ? cnt[base] : 0;
    int v1 = (base + 1 < n) ? cnt[base + 1] : 0;
    int v2 = (base + 2 < n) ? cnt[base + 2] : 0;
    int v3 = (base + 3 < n) ? cnt[base + 3] : 0;
    int s4 = v0 + v1 + v2 + v3;
    sh[t] = s4;
    __syncthreads();
    for (int o = 1; o < 256; o <<= 1) {
        int x = (t >= o) ? sh[t - o] : 0;
        __syncthreads();
        sh[t] += x;
        __syncthreads();
    }
    int p = sh[t] - s4;
    if (t == 255) bs[b] = sh[255];
    if (base < n) out[base] = p;
    p += v0;
    if (base + 1 < n) out[base + 1] = p;
    p += v1;
    if (base + 2 < n) out[base + 2] = p;
    p += v2;
    if (base + 3 < n) out[base + 3] = p;
}

__global__ void k_scan2_dual(int* __restrict__ bsum, int nb,
                             int* __restrict__ totA, int* __restrict__ totB) {
    __shared__ int sh[256];
    int* bs = bsum + blockIdx.x * 256;
    int* tot = blockIdx.x ? totB : totA;
    int t = threadIdx.x;
    int v = (t < nb) ? bs[t] : 0;
    sh[t] = v;
    __syncthreads();
    for (int o = 1; o < 256; o <<= 1) {
        int x = (t >= o) ? sh[t - o] : 0;
        __syncthreads();
        sh[t] += x;
        __syncthreads();
    }
    if (t < nb) bs[t] = sh[t] - v;
    if (t == 255) *tot = sh[255];
}

__global__ void k_scan3b(int* __restrict__ offA, int* __restrict__ offM,
                         const int* __restrict__ bsum, int n) {
    int i = blockIdx.x * 256 + threadIdx.x;
    if (i < n) offA[i] += bsum[i >> 10];
    else if (i < 2 * n) offM[i - n] += bsum[256 + ((i - n) >> 10)];
}

__global__ __launch_bounds__(256) void k_bin(const int* __restrict__ er_src,
                                             const int* __restrict__ er_dst,
                                             const int* __restrict__ ee_src,
                                             const int* __restrict__ ee_dst,
                                             const int* __restrict__ rr_src,
                                             const int* __restrict__ rr_dst,
                                             const float* __restrict__ ee_w,
                                             const int* __restrict__ offA,
                                             const int* __restrict__ offM,
                                             int* __restrict__ recA,
                                             int2* __restrict__ recM,
                                             int E_ER, int E_EE, int E_RR, int NBK) {
    __shared__ int cA[1024], cM[1024];
    int tid = threadIdx.x, blk = blockIdx.x;
    for (int j = tid; j < NBK; j += 256) {
        cA[j] = offA[j * 256 + blk];
        cM[j] = offM[j * 256 + blk];
    }
    __syncthreads();
    int E_T = 2 * E_ER + E_EE + E_RR;
    int stride = gridDim.x * 256;
    for (int e = blk * 256 + tid; e < E_T; e += stride) {
        int i = e;
        if (i < E_ER) {
            int key = er_src[i];
            int p = atomicAdd(&cA[key >> 7], 1);
            recA[p] = er_dst[i] | ((key & 127) << 17);
            continue;
        }
        i -= E_ER;
        int sct, gat;
        float w;
        if (i < E_ER) {
            sct = er_dst[i]; gat = er_src[i]; w = 1.f;
        } else {
            i -= E_ER;
            if (i < E_EE) { sct = ee_src[i]; gat = ee_dst[i]; w = ee_w[i]; }
            else { i -= E_EE; sct = rr_src[i]; gat = rr_dst[i]; w = 1.f; }
        }
        int p = atomicAdd(&cM[sct >> 7], 1);
        recM[p] = make_int2(gat | ((sct & 127) << 17), __float_as_int(w));
    }
}

__global__ __launch_bounds__(256) void k_bucket(const int* __restrict__ offA_h,
                                                const int* __restrict__ offM_h,
                                                const int* __restrict__ recA,
                                                const int2* __restrict__ recM,
                                                int* __restrict__ off_src,
                                                int* __restrict__ off_mean,
                                                int* __restrict__ er_lst,
                                                int2* __restrict__ gpack,
                                                int E_ER, int E_M, int N, int NBK) {
    __shared__ int cnt[256];      // [0:128)=attn, [128:256)=mean
    __shared__ int scanbuf[256];
    __shared__ int cur[256];
    int b = blockIdx.x, tid = threadIdx.x;
    int a0 = offA_h[b * 256];
    int a1 = (b + 1 < NBK) ? offA_h[(b + 1) * 256] : E_ER;
    int m0 = offM_h[b * 256];
    int m1 = (b + 1 < NBK) ? offM_h[(b + 1) * 256] : E_M;
    cnt[tid] = 0;
    __syncthreads();
    for (int i = a0 + tid; i < a1; i += 256) atomicAdd(&cnt[(recA[i] >> 17) & 127], 1);
    for (int i = m0 + tid; i < m1; i += 256) atomicAdd(&cnt[128 + ((recM[i].x >> 17) & 127)], 1);
    __syncthreads();
    int v = cnt[tid];
    scanbuf[tid] = v;
    __syncthreads();
    for (int o = 1; o < 128; o <<= 1) {
        int x = ((tid & 127) >= o) ? scanbuf[tid - o] : 0;
        __syncthreads();
        scanbuf[tid] += x;
        __syncthreads();
    }
    int excl = scanbuf[tid] - v;
    int pos = ((tid < 128) ? a0 : m0) + excl;
    cur[tid] = pos;
    int node = b * 128 + (tid & 127);
    if (node < N) {
        if (tid < 128) off_src[node] = pos;
        else off_mean[node] = pos;
    }
    if (b == 0 && tid == 0) { off_src[N] = E_ER; off_mean[N] = E_M; }
    __syncthreads();
    for (int i = a0 + tid; i < a1; i += 256) {
        int r = recA[i];
        int p = atomicAdd(&cur[(r >> 17) & 127], 1);
        er_lst[p] = r & 0x1FFFF;
    }
    for (int i = m0 + tid; i < m1; i += 256) {
        int2 r = recM[i];
        int p = atomicAdd(&cur[128 + ((r.x >> 17) & 127)], 1);
        gpack[p] = make_int2(r.x & 0x1FFFF, r.y);
    }
}

// ---------------- casts ----------------
// emb f32 -> AE[n][128 + d] (upper half of packed row)
__global__ void k_cast4(const float* __restrict__ src, u16* __restrict__ AE, int n4) {
    int i = blockIdx.x * 256 + threadIdx.x;
    if (i >= n4) return;
    float4 v = ((const float4*)src)[i];
    ushort4 o;
    o.x = f2b(v.x); o.y = f2b(v.y); o.z = f2b(v.z); o.w = f2b(v.w);
    int base = i * 4;
    int n = base >> 7, d = base & 127;
    *(ushort4*)(AE + (size_t)n * 256 + 128 + d) = o;
}

__global__ void k_cast_w(const float* __restrict__ Wattn,
                         const float* __restrict__ W1, const float* __restrict__ W2,
                         const float* __restrict__ W3,
                         u16* __restrict__ Wcat, u16* __restrict__ W123h) {
    int i = blockIdx.x * 256 + threadIdx.x;
    if (i < 32768) {
        int dd = i >> 7, k = i & 127;
        float v = (dd < 128) ? Wattn[(size_t)dd * 256 + k]
                             : Wattn[(size_t)(dd - 128) * 256 + 128 + k];
        Wcat[i] = f2b(v);
        return;
    }
    i -= 32768;
    if (i < 16384) { W123h[i] = f2b(W1[i]); return; }
    i -= 16384;
    if (i < 16384) { W123h[16384 + i] = f2b(W2[i]); return; }
    i -= 16384;
    if (i < 16384) W123h[32768 + i] = f2b(W3[i]);
}

// --- Ar/Ah = emb @ Wcat^T via MFMA (LDS-staged emb tile from AE).
//     Writes Ar -> AE[n][0:128], Ah -> AH[n][0:128]. ---
__global__ __launch_bounds__(256) void k_precompute_mfma(const u16* __restrict__ Wcat,
                                                         u16* __restrict__ AE,
                                                         u16* __restrict__ AH, int N) {
    __shared__ u16 sX[64][136];
    int nb = blockIdx.x * 64;
    int tid = threadIdx.x;
    for (int i = tid; i < 1024; i += 256) {
        int row = i >> 4, c8 = i & 15;
        int n = nb + row;
        uint4 v = make_uint4(0u, 0u, 0u, 0u);
        if (n < N) v = *(const uint4*)(AE + (size_t)n * 256 + 128 + c8 * 8);
        *(uint4*)&sX[row][c8 * 8] = v;
    }
    __syncthreads();
    int wid = tid >> 6, lane = tid & 63;
    int quad = lane >> 4, l15 = lane & 15;
#pragma unroll
    for (int ns = 0; ns < 4; ns++) {
        int dbase = (wid * 4 + ns) * 16;
        bf16x8 b[4];
#pragma unroll
        for (int ks = 0; ks < 4; ks++)
            b[ks] = *(const bf16x8*)(Wcat + (size_t)(dbase + l15) * 128 + ks * 32 + quad * 8);
#pragma unroll
        for (int ms = 0; ms < 4; ms++) {
            f32x4 acc = {0.f, 0.f, 0.f, 0.f};
#pragma unroll
            for (int ks = 0; ks < 4; ks++) {
                bf16x8 a = *(const bf16x8*)&sX[ms * 16 + l15][ks * 32 + quad * 8];
                acc = MFMA16x16(a, b[ks], acc);
            }
#pragma unroll
            for (int r = 0; r < 4; r++) {
                int row = nb + ms * 16 + quad * 4 + r;
                if (row < N) {
                    if (dbase < 128)
                        AE[(size_t)row * 256 + dbase + l15] = f2b(acc[r]);
                    else
                        AH[(size_t)row * 128 + (dbase - 128) + l15] = f2b(acc[r]);
                }
            }
        }
    }
}

// ========== fused gather + epilogue: attn-softmax, mean, 3x tanh(GEMM+bias) ==========
// Block = 64 nodes, 512 threads (8 waves). Phase 0: stage emb tile to LDS.
// Phase 1: DUAL-NODE interleaved quarter-wave gathers — each wave processes its 8
//          nodes as 4 pairs; both nodes' load volleys are in flight simultaneously
//          (8 gather insts outstanding vs 4), two independent shuffle chains.
// Phase 2: MFMA epilogue from LDS, out = sum of 3 tanh(X_arr @ W_arr^T + b_arr).
__global__ __launch_bounds__(512) void k_fuse(const u16* __restrict__ AE,
                                              const u16* __restrict__ AH,
                                              const int* __restrict__ offA,
                                              const int* __restrict__ lstA,
                                              const int* __restrict__ offM,
                                              const int2* __restrict__ gpack,
                                              const float* __restrict__ Wb,
                                              const float* __restrict__ w0w,
                                              const float* __restrict__ w0b,
                                              const u16* __restrict__ W123h,
                                              const float* __restrict__ b1,
                                              const float* __restrict__ b2,
                                              const float* __restrict__ b3,
                                              float* __restrict__ out, int N) {
    __shared__ u16 sX[3][64][136];   // [0]=emb, [1]=attn, [2]=mean ; 52224 B
    int nb = blockIdx.x * 64;
    int tid = threadIdx.x;
    int wid = tid >> 6, lane = tid & 63;
    int quad = lane >> 4, l15 = lane & 15;

    // phase 0: stage emb tile (coalesced)
    for (int j = tid; j < 1024; j += 512) {
        int row = j >> 4, c8 = j & 15;
        int n = nb + row;
        uint4 v = make_uint4(0u, 0u, 0u, 0u);
        if (n < N) v = *(const uint4*)(AE + (size_t)n * 256 + 128 + c8 * 8);
        *(uint4*)&sX[0][row][c8 * 8] = v;
    }

    // lane-invariant 8-dim weight slices (dims l15*8 .. l15*8+7)
    float wwv[8], bbv[8];
#pragma unroll
    for (int j = 0; j < 8; j++) {
        wwv[j] = w0w[l15 * 8 + j];
        bbv[j] = Wb[l15 * 8 + j];
    }
    float w0bias = w0b[0];

    // phase 1: gathers, 2 nodes in flight per wave
    for (int ii = 0; ii < 8; ii += 2) {
        int localA = wid * 8 + ii;
        int localB = localA + 1;
        int nodeA = nb + localA;
        int nodeB = nb + localB;
        int nA = nodeA < N ? nodeA : N - 1;
        int nB = nodeB < N ? nodeB : N - 1;

        // ---- attention softmax-weighted aggregate (pair) ----
        bf16x8 ahA = *(const bf16x8*)(AH + (size_t)nA * 128 + l15 * 8);
        bf16x8 ahB = *(const bf16x8*)(AH + (size_t)nB * 128 + l15 * 8);
        const u32* ahAp = (const u32*)&ahA;
        const u32* ahBp = (const u32*)&ahB;
        float haxbA[8], haxbB[8];
#pragma unroll
        for (int j = 0; j < 4; j++) {
            haxbA[2 * j]     = b2f(ahAp[j]) + bbv[2 * j];
            haxbA[2 * j + 1] = b2f(ahAp[j] >> 16) + bbv[2 * j + 1];
            haxbB[2 * j]     = b2f(ahBp[j]) + bbv[2 * j];
            haxbB[2 * j + 1] = b2f(ahBp[j] >> 16) + bbv[2 * j + 1];
        }
        int sA0 = offA[nA], sA1 = offA[nA + 1];
        int sB0 = offA[nB], sB1 = offA[nB + 1];
        float accxA[8] = {0.f, 0.f, 0.f, 0.f, 0.f, 0.f, 0.f, 0.f};
        float accxB[8] = {0.f, 0.f, 0.f, 0.f, 0.f, 0.f, 0.f, 0.f};
        float lsumA = 0.f, lsumB = 0.f;
        for (int sA = sA0, sB = sB0; sA < sA1 || sB < sB1; sA += 8, sB += 8) {
            int a0 = sA + quad, a1 = sA + 4 + quad;
            int b0 = sB + quad, b1 = sB + 4 + quad;
            bool vA0 = a0 < sA1, vA1 = a1 < sA1;
            bool vB0 = b0 < sB1, vB1 = b1 < sB1;
            int dA0 = lstA[vA0 ? a0 : sA0];
            int dA1 = lstA[vA1 ? a1 : sA0];
            int dB0 = lstA[vB0 ? b0 : sB0];
            int dB1 = lstA[vB1 ? b1 : sB0];
            bf16x8 arA0 = *(const bf16x8*)(AE + (size_t)dA0 * 256 + l15 * 8);
            bf16x8 arA1 = *(const bf16x8*)(AE + (size_t)dA1 * 256 + l15 * 8);
            bf16x8 arB0 = *(const bf16x8*)(AE + (size_t)dB0 * 256 + l15 * 8);
            bf16x8 arB1 = *(const bf16x8*)(AE + (size_t)dB1 * 256 + l15 * 8);
            bf16x8 evA0 = *(const bf16x8*)(AE + (size_t)dA0 * 256 + 128 + l15 * 8);
            bf16x8 evA1 = *(const bf16x8*)(AE + (size_t)dA1 * 256 + 128 + l15 * 8);
            bf16x8 evB0 = *(const bf16x8*)(AE + (size_t)dB0 * 256 + 128 + l15 * 8);
            bf16x8 evB1 = *(const bf16x8*)(AE + (size_t)dB1 * 256 + 128 + l15 * 8);
            const u32* pA0p = (const u32*)&arA0;
            const u32* pA1p = (const u32*)&arA1;
            const u32* pB0p = (const u32*)&arB0;
            const u32* pB1p = (const u32*)&arB1;
            float pA0 = 0.f, pA1 = 0.f, pB0 = 0.f, pB1 = 0.f;
#pragma unroll
            for (int j = 0; j < 4; j++) {
                pA0 += tanh_fast(b2f(pA0p[j]) + haxbA[2 * j]) * wwv[2 * j] +
                       tanh_fast(b2f(pA0p[j] >> 16) + haxbA[2 * j + 1]) * wwv[2 * j + 1];
                pA1 += tanh_fast(b2f(pA1p[j]) + haxbA[2 * j]) * wwv[2 * j] +
                       tanh_fast(b2f(pA1p[j] >> 16) + haxbA[2 * j + 1]) * wwv[2 * j + 1];
                pB0 += tanh_fast(b2f(pB0p[j]) + haxbB[2 * j]) * wwv[2 * j] +
                       tanh_fast(b2f(pB0p[j] >> 16) + haxbB[2 * j + 1]) * wwv[2 * j + 1];
                pB1 += tanh_fast(b2f(pB1p[j]) + haxbB[2 * j]) * wwv[2 * j] +
                       tanh_fast(b2f(pB1p[j] >> 16) + haxbB[2 * j + 1]) * wwv[2 * j + 1];
            }
#pragma unroll
            for (int o = 1; o < 16; o <<= 1) {
                pA0 += __shfl_xor(pA0, o);
                pA1 += __shfl_xor(pA1, o);
                pB0 += __shfl_xor(pB0, o);
                pB1 += __shfl_xor(pB1, o);
            }
            float eA0 = vA0 ? __expf(pA0 + w0bias) : 0.f;
            float eA1 = vA1 ? __expf(pA1 + w0bias) : 0.f;
            float eB0 = vB0 ? __expf(pB0 + w0bias) : 0.f;
            float eB1 = vB1 ? __expf(pB1 + w0bias) : 0.f;
            lsumA += eA0 + eA1;
            lsumB += eB0 + eB1;
            const u32* eA0p = (const u32*)&evA0;
            const u32* eA1p = (const u32*)&evA1;
            const u32* eB0p = (const u32*)&evB0;
            const u32* eB1p = (const u32*)&evB1;
#pragma unroll
            for (int j = 0; j < 4; j++) {
                accxA[2 * j]     += eA0 * b2f(eA0p[j]) + eA1 * b2f(eA1p[j]);
                accxA[2 * j + 1] += eA0 * b2f(eA0p[j] >> 16) + eA1 * b2f(eA1p[j] >> 16);
                accxB[2 * j]     += eB0 * b2f(eB0p[j]) + eB1 * b2f(eB1p[j]);
                accxB[2 * j + 1] += eB0 * b2f(eB0p[j] >> 16) + eB1 * b2f(eB1p[j] >> 16);
            }
        }
#pragma unroll
        for (int j = 0; j < 8; j++) {
            accxA[j] += __shfl_xor(accxA[j], 16);
            accxA[j] += __shfl_xor(accxA[j], 32);
            accxB[j] += __shfl_xor(accxB[j], 16);
            accxB[j] += __shfl_xor(accxB[j], 32);
        }
        lsumA += __shfl_xor(lsumA, 16);
        lsumA += __shfl_xor(lsumA, 32);
        lsumB += __shfl_xor(lsumB, 16);
        lsumB += __shfl_xor(lsumB, 32);
        float invA = 1.f / (lsumA + 1e-9f);
        float invB = 1.f / (lsumB + 1e-9f);
        if (quad == 0) {
            uint4 o4;
            u32* op = (u32*)&o4;
            if (nodeA < N) {
#pragma unroll
                for (int j = 0; j < 4; j++)
                    op[j] = (u32)f2b(accxA[2 * j] * invA) |
                            ((u32)f2b(accxA[2 * j + 1] * invA) << 16);
                *(uint4*)&sX[1][localA][l15 * 8] = o4;
            }
            if (nodeB < N) {
#pragma unroll
                for (int j = 0; j < 4; j++)
                    op[j] = (u32)f2b(accxB[2 * j] * invB) |
                            ((u32)f2b(accxB[2 * j + 1] * invB) << 16);
                *(uint4*)&sX[1][localB][l15 * 8] = o4;
            }
        }

        // ---- weighted mean aggregate (pair) ----
        int mA0 = offM[nA], mA1 = offM[nA + 1];
        int mB0 = offM[nB], mB1 = offM[nB + 1];
        float accmA[8] = {0.f, 0.f, 0.f, 0.f, 0.f, 0.f, 0.f, 0.f};
        float accmB[8] = {0.f, 0.f, 0.f, 0.f, 0.f, 0.f, 0.f, 0.f};
        float cA = 0.f, cB = 0.f;
        for (int sA = mA0, sB = mB0; sA < mA1 || sB < mB1; sA += 8, sB += 8) {
            int a0 = sA + quad, a1 = sA + 4 + quad;
            int b0 = sB + quad, b1 = sB + 4 + quad;
            bool vA0 = a0 < mA1, vA1 = a1 < mA1;
            bool vB0 = b0 < mB1, vB1 = b1 < mB1;
            int2 pkA0 = gpack[vA0 ? a0 : mA0];
            int2 pkA1 = gpack[vA1 ? a1 : mA0];
            int2 pkB0 = gpack[vB0 ? b0 : mB0];
            int2 pkB1 = gpack[vB1 ? b1 : mB0];
            float wA0 = vA0 ? __int_as_float(pkA0.y) : 0.f;
            float wA1 = vA1 ? __int_as_float(pkA1.y) : 0.f;
            float wB0 = vB0 ? __int_as_float(pkB0.y) : 0.f;
            float wB1 = vB1 ? __int_as_float(pkB1.y) : 0.f;
            bf16x8 evA0 = *(const bf16x8*)(AE + (size_t)pkA0.x * 256 + 128 + l15 * 8);
            bf16x8 evA1 = *(const bf16x8*)(AE + (size_t)pkA1.x * 256 + 128 + l15 * 8);
            bf16x8 evB0 = *(const bf16x8*)(AE + (size_t)pkB0.x * 256 + 128 + l15 * 8);
            bf16x8 evB1 = *(const bf16x8*)(AE + (size_t)pkB1.x * 256 + 128 + l15 * 8);
            const u32* eA0p = (const u32*)&evA0;
            const u32* eA1p = (const u32*)&evA1;
            const u32* eB0p = (const u32*)&evB0;
            const u32* eB1p = (const u32*)&evB1;
#pragma unroll
            for (int j = 0; j < 4; j++) {
                accmA[2 * j]     += wA0 * b2f(eA0p[j]) + wA1 * b2f(eA1p[j]);
                accmA[2 * j + 1] += wA0 * b2f(eA0p[j] >> 16) + wA1 * b2f(eA1p[j] >> 16);
                accmB[2 * j]     += wB0 * b2f(eB0p[j]) + wB1 * b2f(eB1p[j]);
                accmB[2 * j + 1] += wB0 * b2f(eB0p[j] >> 16) + wB1 * b2f(eB1p[j] >> 16);
            }
            cA += wA0 + wA1;
            cB += wB0 + wB1;
        }
#pragma unroll
        for (int j = 0; j < 8; j++) {
            accmA[j] += __shfl_xor(accmA[j], 16);
            accmA[j] += __shfl_xor(accmA[j], 32);
            accmB[j] += __shfl_xor(accmB[j], 16);
            accmB[j] += __shfl_xor(accmB[j], 32);
        }
        cA += __shfl_xor(cA, 16);
        cA += __shfl_xor(cA, 32);
        cB += __shfl_xor(cB, 16);
        cB += __shfl_xor(cB, 32);
        cA = cA > 1.f ? cA : 1.f;
        cB = cB > 1.f ? cB : 1.f;
        float minvA = 1.f / cA;
        float minvB = 1.f / cB;
        if (quad == 0) {
            uint4 o4;
            u32* op = (u32*)&o4;
            if (nodeA < N) {
#pragma unroll
                for (int j = 0; j < 4; j++)
                    op[j] = (u32)f2b(accmA[2 * j] * minvA) |
                            ((u32)f2b(accmA[2 * j + 1] * minvA) << 16);
                *(uint4*)&sX[2][localA][l15 * 8] = o4;
            }
            if (nodeB < N) {
#pragma unroll
                for (int j = 0; j < 4; j++)
                    op[j] = (u32)f2b(accmB[2 * j] * minvB) |
                            ((u32)f2b(accmB[2 * j + 1] * minvB) << 16);
                *(uint4*)&sX[2][localB][l15 * 8] = o4;
            }
        }
    }
    __syncthreads();

    // phase 2: MFMA epilogue. wave wid owns output d-tile [wid*16, wid*16+16).
    int d = wid * 16 + l15;
    const float* biases[3] = {b1, b2, b3};
    f32x4 res0 = {0.f, 0.f, 0.f, 0.f};
    f32x4 res1 = {0.f, 0.f, 0.f, 0.f};
    f32x4 res2 = {0.f, 0.f, 0.f, 0.f};
    f32x4 res3 = {0.f, 0.f, 0.f, 0.f};
#pragma unroll
    for (int arr = 0; arr < 3; arr++) {
        bf16x8 b[4];
#pragma unroll
        for (int ks = 0; ks < 4; ks++)
            b[ks] = *(const bf16x8*)(W123h + (size_t)arr * 16384 +
                                     (size_t)d * 128 + ks * 32 + quad * 8);
        float bias = biases[arr][d];
#pragma unroll
        for (int ms = 0; ms < 4; ms++) {
            f32x4 acc = {0.f, 0.f, 0.f, 0.f};
#pragma unroll
            for (int ks = 0; ks < 4; ks++) {
                bf16x8 a = *(const bf16x8*)&sX[arr][ms * 16 + l15][ks * 32 + quad * 8];
                acc = MFMA16x16(a, b[ks], acc);
            }
            f32x4& res = (ms == 0) ? res0 : (ms == 1) ? res1 : (ms == 2) ? res2 : res3;
#pragma unroll
            for (int r = 0; r < 4; r++)
                res[r] += tanh_fast(acc[r] + bias);
        }
    }
#pragma unroll
    for (int ms = 0; ms < 4; ms++) {
        f32x4& res = (ms == 0) ? res0 : (ms == 1) ? res1 : (ms == 2) ? res2 : res3;
#pragma unroll
        for (int r = 0; r < 4; r++) {
            int orow = nb + ms * 16 + quad * 4 + r;
            if (orow < N)
                out[(size_t)orow * 128 + d] = res[r];
        }
    }
}

extern "C" void kernel_launch(void* const* d_in, const int* in_sizes, int n_in,
                              void* d_out, int out_size, void* d_ws, size_t ws_size,
                              hipStream_t stream) {
    const float* emb     = (const float*)d_in[0];
    const int*   er_src  = (const int*)d_in[1];
    const int*   er_dst  = (const int*)d_in[2];
    const int*   ee_src  = (const int*)d_in[3];
    const int*   ee_dst  = (const int*)d_in[4];
    const float* ee_w    = (const float*)d_in[5];
    const int*   rr_src  = (const int*)d_in[6];
    const int*   rr_dst  = (const int*)d_in[7];
    const float* Wattn   = (const float*)d_in[8];
    const float* Wattn_b = (const float*)d_in[9];
    const float* w0w     = (const float*)d_in[10];
    const float* w0b     = (const float*)d_in[11];
    const float* W1      = (const float*)d_in[12];
    const float* b1      = (const float*)d_in[13];
    const float* W2      = (const float*)d_in[14];
    const float* b2      = (const float*)d_in[15];
    const float* W3      = (const float*)d_in[16];
    const float* b3      = (const float*)d_in[17];
    float* out = (float*)d_out;

    int N    = in_sizes[0] / D;
    int E_ER = in_sizes[1];
    int E_EE = in_sizes[3];
    int E_RR = in_sizes[6];
    int E_M  = E_ER + E_EE + E_RR;

    int NBK = (N + 127) >> 7;        // buckets of 128 nodes (<=1024 buckets)
    int HL  = NBK * 256;             // hist entries per list ([bucket][block], 256 blocks)

    char* ws = (char*)d_ws;
    size_t off_b = 0;
    auto alloc = [&](size_t bytes) -> void* {
        void* p = ws + off_b;
        off_b += (bytes + 255) & ~(size_t)255;
        return p;
    };
    u16*   AE     = (u16*)alloc((size_t)N * 256 * 2);   // [Ar | emb] packed rows
    u16*   AH     = (u16*)alloc((size_t)N * 128 * 2);   // Ah rows
    u16*   Wcat_h = (u16*)alloc(256 * 128 * 2);
    u16*   W123h  = (u16*)alloc(3 * 128 * 128 * 2);
    int*   off_src  = (int*)alloc((size_t)(N + 1) * 4);
    int*   off_mean = (int*)alloc((size_t)(N + 1) * 4);
    int*   bsum     = (int*)alloc(514 * 4);  // [bsumA | bsumB | 2 scratch totals]
    int*   er_lst   = (int*)alloc((size_t)E_ER * 4);
    int2*  gpack    = (int2*)alloc((size_t)E_M * 8);
    int2*  recM     = (int2*)alloc((size_t)E_M * 8);
    int*   recA     = (int*)alloc((size_t)E_ER * 4);
    int*   hist2    = (int*)alloc((size_t)2 * HL * 4);
    int*   offHA    = (int*)alloc((size_t)HL * 4);
    int*   offHM    = (int*)alloc((size_t)HL * 4);

    int nbh = (HL + 1023) / 1024;  // <= 256

    // --- casts (independent) ---
    k_cast4<<<((N * 128 / 4) + 255) / 256, 256, 0, stream>>>(emb, AE, N * 128 / 4);
    k_cast_w<<<(81920 + 255) / 256, 256, 0, stream>>>(Wattn, W1, W2, W3, Wcat_h, W123h);

    // --- bucketed CSR build ---
    k_bhist<<<256, 256, 0, stream>>>(er_src, er_dst, ee_src, rr_src,
                                     hist2, hist2 + HL, E_ER, E_EE, E_RR, NBK);
    k_scan1_dual<<<2 * nbh, 256, 0, stream>>>(hist2, HL, offHA, offHM, bsum, nbh);
    k_scan2_dual<<<2, 256, 0, stream>>>(bsum, nbh, bsum + 512, bsum + 513);
    k_scan3b<<<(2 * HL + 255) / 256, 256, 0, stream>>>(offHA, offHM, bsum, HL);
    k_bin<<<256, 256, 0, stream>>>(er_src, er_dst, ee_src, ee_dst, rr_src, rr_dst, ee_w,
                                   offHA, offHM, recA, recM, E_ER, E_EE, E_RR, NBK);
    k_bucket<<<NBK, 256, 0, stream>>>(offHA, offHM, recA, recM,
                                      off_src, off_mean, er_lst, gpack,
                                      E_ER, E_M, N, NBK);

    // --- compute ---
    k_precompute_mfma<<<(N + 63) / 64, 256, 0, stream>>>(Wcat_h, AE, AH, N);
    k_fuse<<<(N + 63) / 64, 512, 0, stream>>>(AE, AH, off_src, er_lst, off_mean, gpack,
                                              Wattn_b, w0w, w0b, W123h,
                                              b1, b2, b3, out, N);
}

// Round 13
// 508.440 us; speedup vs baseline: 1.1520x; 1.1520x over previous
//
#include <hip/hip_runtime.h>

typedef unsigned int u32;
typedef unsigned short u16;

#define D 128

typedef __attribute__((ext_vector_type(8))) short bf16x8;
typedef __attribute__((ext_vector_type(4))) float f32x4;
#define MFMA16x16(a, b, c) __builtin_amdgcn_mfma_f32_16x16x32_bf16(a, b, c, 0, 0, 0)

__device__ inline float b2f(u32 h) { return __uint_as_float((h & 0xffffu) << 16); }
__device__ inline u16 f2b(float f) {
    u32 u = __float_as_uint(f);
    return (u16)((u + 0x7fffu + ((u >> 16) & 1u)) >> 16);
}
__device__ inline float tanh_fast(float x) {
    x = fminf(fmaxf(x, -15.f), 15.f);
    float e = __expf(2.f * x);
    return (e - 1.f) * __builtin_amdgcn_rcpf(e + 1.f);
}

// ===================== bucketed CSR build (no global atomics) =====================
// Buckets of 128 nodes: bucket = node >> 7, local = node & 127.
// hist layout: hist[bucket][block], block-count fixed at 256.

__global__ __launch_bounds__(256) void k_bhist(const int* __restrict__ er_src,
                                               const int* __restrict__ er_dst,
                                               const int* __restrict__ ee_src,
                                               const int* __restrict__ rr_src,
                                               int* __restrict__ histA,
                                               int* __restrict__ histM,
                                               int E_ER, int E_EE, int E_RR, int NBK) {
    __shared__ int hA[1024], hM[1024];
    int tid = threadIdx.x;
    for (int j = tid; j < NBK; j += 256) { hA[j] = 0; hM[j] = 0; }
    __syncthreads();
    int E_T = 2 * E_ER + E_EE + E_RR;
    int stride = gridDim.x * 256;
    for (int e = blockIdx.x * 256 + tid; e < E_T; e += stride) {
        int i = e;
        if (i < E_ER) { atomicAdd(&hA[er_src[i] >> 7], 1); continue; }
        i -= E_ER;
        int key;
        if (i < E_ER) key = er_dst[i];
        else {
            i -= E_ER;
            key = (i < E_EE) ? ee_src[i] : rr_src[i - E_EE];
        }
        atomicAdd(&hM[key >> 7], 1);
    }
    __syncthreads();
    for (int j = tid; j < NBK; j += 256) {
        histA[j * 256 + blockIdx.x] = hA[j];
        histM[j * 256 + blockIdx.x] = hM[j];
    }
}

__global__ void k_scan1_dual(const int* __restrict__ cnt2, int n,
                             int* __restrict__ off_src, int* __restrict__ off_mean,
                             int* __restrict__ bsum, int nbs) {
    __shared__ int sh[256];
    int b = blockIdx.x;
    const int* cnt = cnt2;
    int* out = off_src;
    int* bs = bsum;
    if (b >= nbs) { b -= nbs; cnt = cnt2 + n; out = off_mean; bs = bsum + 256; }
    int t = threadIdx.x;
    int base = b * 1024 + t * 4;
    int v0 = (base < n) ? cnt[base] : 0;
    int v1 = (base + 1 < n) ? cnt[base + 1] : 0;
    int v2 = (base + 2 < n) ? cnt[base + 2] : 0;
    int v3 = (base + 3 < n) ? cnt[base + 3] : 0;
    int s4 = v0 + v1 + v2 + v3;
    sh[t] = s4;
    __syncthreads();
    for (int o = 1; o < 256; o <<= 1) {
        int x = (t >= o) ? sh[t - o] : 0;
        __syncthreads();
        sh[t] += x;
        __syncthreads();
    }
    int p = sh[t] - s4;
    if (t == 255) bs[b] = sh[255];
    if (base < n) out[base] = p;
    p += v0;
    if (base + 1 < n) out[base + 1] = p;
    p += v1;
    if (base + 2 < n) out[base + 2] = p;
    p += v2;
    if (base + 3 < n) out[base + 3] = p;
}

__global__ void k_scan2_dual(int* __restrict__ bsum, int nb,
                             int* __restrict__ totA, int* __restrict__ totB) {
    __shared__ int sh[256];
    int* bs = bsum + blockIdx.x * 256;
    int* tot = blockIdx.x ? totB : totA;
    int t = threadIdx.x;
    int v = (t < nb) ? bs[t] : 0;
    sh[t] = v;
    __syncthreads();
    for (int o = 1; o < 256; o <<= 1) {
        int x = (t >= o) ? sh[t - o] : 0;
        __syncthreads();
        sh[t] += x;
        __syncthreads();
    }
    if (t < nb) bs[t] = sh[t] - v;
    if (t == 255) *tot = sh[255];
}

__global__ void k_scan3b(int* __restrict__ offA, int* __restrict__ offM,
                         const int* __restrict__ bsum, int n) {
    int i = blockIdx.x * 256 + threadIdx.x;
    if (i < n) offA[i] += bsum[i >> 10];
    else if (i < 2 * n) offM[i - n] += bsum[256 + ((i - n) >> 10)];
}

__global__ __launch_bounds__(256) void k_bin(const int* __restrict__ er_src,
                                             const int* __restrict__ er_dst,
                                             const int* __restrict__ ee_src,
                                             const int* __restrict__ ee_dst,
                                             const int* __restrict__ rr_src,
                                             const int* __restrict__ rr_dst,
                                             const float* __restrict__ ee_w,
                                             const int* __restrict__ offA,
                                             const int* __restrict__ offM,
                                             int* __restrict__ recA,
                                             int2* __restrict__ recM,
                                             int E_ER, int E_EE, int E_RR, int NBK) {
    __shared__ int cA[1024], cM[1024];
    int tid = threadIdx.x, blk = blockIdx.x;
    for (int j = tid; j < NBK; j += 256) {
        cA[j] = offA[j * 256 + blk];
        cM[j] = offM[j * 256 + blk];
    }
    __syncthreads();
    int E_T = 2 * E_ER + E_EE + E_RR;
    int stride = gridDim.x * 256;
    for (int e = blk * 256 + tid; e < E_T; e += stride) {
        int i = e;
        if (i < E_ER) {
            int key = er_src[i];
            int p = atomicAdd(&cA[key >> 7], 1);
            recA[p] = er_dst[i] | ((key & 127) << 17);
            continue;
        }
        i -= E_ER;
        int sct, gat;
        float w;
        if (i < E_ER) {
            sct = er_dst[i]; gat = er_src[i]; w = 1.f;
        } else {
            i -= E_ER;
            if (i < E_EE) { sct = ee_src[i]; gat = ee_dst[i]; w = ee_w[i]; }
            else { i -= E_EE; sct = rr_src[i]; gat = rr_dst[i]; w = 1.f; }
        }
        int p = atomicAdd(&cM[sct >> 7], 1);
        recM[p] = make_int2(gat | ((sct & 127) << 17), __float_as_int(w));
    }
}

__global__ __launch_bounds__(256) void k_bucket(const int* __restrict__ offA_h,
                                                const int* __restrict__ offM_h,
                                                const int* __restrict__ recA,
                                                const int2* __restrict__ recM,
                                                int* __restrict__ off_src,
                                                int* __restrict__ off_mean,
                                                int* __restrict__ er_lst,
                                                int2* __restrict__ gpack,
                                                int E_ER, int E_M, int N, int NBK) {
    __shared__ int cnt[256];      // [0:128)=attn, [128:256)=mean
    __shared__ int scanbuf[256];
    __shared__ int cur[256];
    int b = blockIdx.x, tid = threadIdx.x;
    int a0 = offA_h[b * 256];
    int a1 = (b + 1 < NBK) ? offA_h[(b + 1) * 256] : E_ER;
    int m0 = offM_h[b * 256];
    int m1 = (b + 1 < NBK) ? offM_h[(b + 1) * 256] : E_M;
    cnt[tid] = 0;
    __syncthreads();
    for (int i = a0 + tid; i < a1; i += 256) atomicAdd(&cnt[(recA[i] >> 17) & 127], 1);
    for (int i = m0 + tid; i < m1; i += 256) atomicAdd(&cnt[128 + ((recM[i].x >> 17) & 127)], 1);
    __syncthreads();
    int v = cnt[tid];
    scanbuf[tid] = v;
    __syncthreads();
    for (int o = 1; o < 128; o <<= 1) {
        int x = ((tid & 127) >= o) ? scanbuf[tid - o] : 0;
        __syncthreads();
        scanbuf[tid] += x;
        __syncthreads();
    }
    int excl = scanbuf[tid] - v;
    int pos = ((tid < 128) ? a0 : m0) + excl;
    cur[tid] = pos;
    int node = b * 128 + (tid & 127);
    if (node < N) {
        if (tid < 128) off_src[node] = pos;
        else off_mean[node] = pos;
    }
    if (b == 0 && tid == 0) { off_src[N] = E_ER; off_mean[N] = E_M; }
    __syncthreads();
    for (int i = a0 + tid; i < a1; i += 256) {
        int r = recA[i];
        int p = atomicAdd(&cur[(r >> 17) & 127], 1);
        er_lst[p] = r & 0x1FFFF;
    }
    for (int i = m0 + tid; i < m1; i += 256) {
        int2 r = recM[i];
        int p = atomicAdd(&cur[128 + ((r.x >> 17) & 127)], 1);
        gpack[p] = make_int2(r.x & 0x1FFFF, r.y);
    }
}

// ---------------- casts ----------------
__global__ void k_cast4(const float* __restrict__ src, u16* __restrict__ dst, int n4) {
    int i = blockIdx.x * 256 + threadIdx.x;
    if (i >= n4) return;
    float4 v = ((const float4*)src)[i];
    ushort4 o;
    o.x = f2b(v.x); o.y = f2b(v.y); o.z = f2b(v.z); o.w = f2b(v.w);
    ((ushort4*)dst)[i] = o;
}

__global__ void k_cast_w(const float* __restrict__ Wattn,
                         const float* __restrict__ W1, const float* __restrict__ W2,
                         const float* __restrict__ W3,
                         u16* __restrict__ Wcat, u16* __restrict__ W123h) {
    int i = blockIdx.x * 256 + threadIdx.x;
    if (i < 32768) {
        int dd = i >> 7, k = i & 127;
        float v = (dd < 128) ? Wattn[(size_t)dd * 256 + k]
                             : Wattn[(size_t)(dd - 128) * 256 + 128 + k];
        Wcat[i] = f2b(v);
        return;
    }
    i -= 32768;
    if (i < 16384) { W123h[i] = f2b(W1[i]); return; }
    i -= 16384;
    if (i < 16384) { W123h[16384 + i] = f2b(W2[i]); return; }
    i -= 16384;
    if (i < 16384) W123h[32768 + i] = f2b(W3[i]);
}

// --- A = embh @ Wcat^T via MFMA (LDS-staged X tile; 17 KB, conflict-free).
//     A[n][dd] bf16, dd in [0,256) ---
__global__ __launch_bounds__(256) void k_precompute_mfma(const u16* __restrict__ embh,
                                                         const u16* __restrict__ Wcat,
                                                         u16* __restrict__ A, int N) {
    __shared__ u16 sX[64][136];
    int nb = blockIdx.x * 64;
    int tid = threadIdx.x;
    for (int i = tid; i < 1024; i += 256) {
        int row = i >> 4, c8 = i & 15;
        int n = nb + row;
        uint4 v = make_uint4(0u, 0u, 0u, 0u);
        if (n < N) v = *(const uint4*)(embh + (size_t)n * 128 + c8 * 8);
        *(uint4*)&sX[row][c8 * 8] = v;
    }
    __syncthreads();
    int wid = tid >> 6, lane = tid & 63;
    int quad = lane >> 4, l15 = lane & 15;
#pragma unroll
    for (int ns = 0; ns < 4; ns++) {
        int dbase = (wid * 4 + ns) * 16;
        bf16x8 b[4];
#pragma unroll
        for (int ks = 0; ks < 4; ks++)
            b[ks] = *(const bf16x8*)(Wcat + (size_t)(dbase + l15) * 128 + ks * 32 + quad * 8);
#pragma unroll
        for (int ms = 0; ms < 4; ms++) {
            f32x4 acc = {0.f, 0.f, 0.f, 0.f};
#pragma unroll
            for (int ks = 0; ks < 4; ks++) {
                bf16x8 a = *(const bf16x8*)&sX[ms * 16 + l15][ks * 32 + quad * 8];
                acc = MFMA16x16(a, b[ks], acc);
            }
#pragma unroll
            for (int r = 0; r < 4; r++) {
                int row = nb + ms * 16 + quad * 4 + r;
                if (row < N) A[(size_t)row * 256 + dbase + l15] = f2b(acc[r]);
            }
        }
    }
}

// ========== fused gather + epilogue: attn-softmax, mean, 3x tanh(GEMM+bias) ==========
// Block = 64 nodes, 512 threads (8 waves). Phase 0: stage emb tile to LDS.
// Phase 1: quarter-wave edge parallelism — each 16-lane quad owns one edge, a lane
//          covers 8 dims via b128 loads; 8 edges in flight per iteration; 4-level
//          intra-quad shuffle reduce; cross-quad combine once per node.
// Phase 2: MFMA epilogue from LDS, out = sum of 3 tanh(X_arr @ W_arr^T + b_arr).
__global__ __launch_bounds__(512) void k_fuse(const u16* __restrict__ A,
                                              const int* __restrict__ offA,
                                              const int* __restrict__ lstA,
                                              const int* __restrict__ offM,
                                              const int2* __restrict__ gpack,
                                              const u16* __restrict__ embh,
                                              const float* __restrict__ Wb,
                                              const float* __restrict__ w0w,
                                              const float* __restrict__ w0b,
                                              const u16* __restrict__ W123h,
                                              const float* __restrict__ b1,
                                              const float* __restrict__ b2,
                                              const float* __restrict__ b3,
                                              float* __restrict__ out, int N) {
    __shared__ u16 sX[3][64][136];   // [0]=emb, [1]=attn, [2]=mean ; 52224 B
    int nb = blockIdx.x * 64;
    int tid = threadIdx.x;
    int wid = tid >> 6, lane = tid & 63;
    int quad = lane >> 4, l15 = lane & 15;

    // phase 0: stage emb tile (coalesced)
    for (int j = tid; j < 1024; j += 512) {
        int row = j >> 4, c8 = j & 15;
        int n = nb + row;
        uint4 v = make_uint4(0u, 0u, 0u, 0u);
        if (n < N) v = *(const uint4*)(embh + (size_t)n * 128 + c8 * 8);
        *(uint4*)&sX[0][row][c8 * 8] = v;
    }

    // lane-invariant 8-dim weight slices (dims l15*8 .. l15*8+7)
    float wwv[8], bbv[8];
#pragma unroll
    for (int j = 0; j < 8; j++) {
        wwv[j] = w0w[l15 * 8 + j];
        bbv[j] = Wb[l15 * 8 + j];
    }
    float w0bias = w0b[0];

    // phase 1: gathers (8 nodes per wave)
    for (int i = 0; i < 8; ++i) {
        int local = wid * 8 + i;
        int node = nb + local;
        if (node < N) {
            // ---- attention softmax-weighted aggregate ----
            bf16x8 ah8 = *(const bf16x8*)(A + (size_t)node * 256 + 128 + l15 * 8);
            const u32* ahp = (const u32*)&ah8;
            float haxb[8];
#pragma unroll
            for (int j = 0; j < 4; j++) {
                haxb[2 * j]     = b2f(ahp[j]) + bbv[2 * j];
                haxb[2 * j + 1] = b2f(ahp[j] >> 16) + bbv[2 * j + 1];
            }
            int s0 = offA[node], s1 = offA[node + 1];
            float accx[8] = {0.f, 0.f, 0.f, 0.f, 0.f, 0.f, 0.f, 0.f};
            float lsum = 0.f;
            for (int s = s0; s < s1; s += 8) {
                int i0 = s + quad, i1 = s + 4 + quad;
                bool va = i0 < s1, vb = i1 < s1;
                int d0 = lstA[va ? i0 : s0];
                int d1 = lstA[vb ? i1 : s0];
                bf16x8 ar0 = *(const bf16x8*)(A + (size_t)d0 * 256 + l15 * 8);
                bf16x8 ar1 = *(const bf16x8*)(A + (size_t)d1 * 256 + l15 * 8);
                bf16x8 ev0 = *(const bf16x8*)(embh + (size_t)d0 * 128 + l15 * 8);
                bf16x8 ev1 = *(const bf16x8*)(embh + (size_t)d1 * 128 + l15 * 8);
                const u32* a0p = (const u32*)&ar0;
                const u32* a1p = (const u32*)&ar1;
                float p0 = 0.f, p1 = 0.f;
#pragma unroll
                for (int j = 0; j < 4; j++) {
                    p0 += tanh_fast(b2f(a0p[j]) + haxb[2 * j]) * wwv[2 * j] +
                          tanh_fast(b2f(a0p[j] >> 16) + haxb[2 * j + 1]) * wwv[2 * j + 1];
                    p1 += tanh_fast(b2f(a1p[j]) + haxb[2 * j]) * wwv[2 * j] +
                          tanh_fast(b2f(a1p[j] >> 16) + haxb[2 * j + 1]) * wwv[2 * j + 1];
                }
#pragma unroll
                for (int o = 1; o < 16; o <<= 1) {
                    p0 += __shfl_xor(p0, o);
                    p1 += __shfl_xor(p1, o);
                }
                float e0 = va ? __expf(p0 + w0bias) : 0.f;
                float e1 = vb ? __expf(p1 + w0bias) : 0.f;
                lsum += e0 + e1;
                const u32* e0p = (const u32*)&ev0;
                const u32* e1p = (const u32*)&ev1;
#pragma unroll
                for (int j = 0; j < 4; j++) {
                    accx[2 * j]     += e0 * b2f(e0p[j]) + e1 * b2f(e1p[j]);
                    accx[2 * j + 1] += e0 * b2f(e0p[j] >> 16) + e1 * b2f(e1p[j] >> 16);
                }
            }
            // cross-quad combine (lanes with equal l15 hold the same dims)
#pragma unroll
            for (int j = 0; j < 8; j++) {
                accx[j] += __shfl_xor(accx[j], 16);
                accx[j] += __shfl_xor(accx[j], 32);
            }
            lsum += __shfl_xor(lsum, 16);
            lsum += __shfl_xor(lsum, 32);
            float inv = 1.f / (lsum + 1e-9f);
            if (quad == 0) {
                uint4 o4;
                u32* op = (u32*)&o4;
#pragma unroll
                for (int j = 0; j < 4; j++)
                    op[j] = (u32)f2b(accx[2 * j] * inv) |
                            ((u32)f2b(accx[2 * j + 1] * inv) << 16);
                *(uint4*)&sX[1][local][l15 * 8] = o4;
            }

            // ---- weighted mean aggregate ----
            s0 = offM[node]; s1 = offM[node + 1];
            float accm[8] = {0.f, 0.f, 0.f, 0.f, 0.f, 0.f, 0.f, 0.f};
            float c = 0.f;
            for (int s = s0; s < s1; s += 8) {
                int i0 = s + quad, i1 = s + 4 + quad;
                bool va = i0 < s1, vb = i1 < s1;
                int2 pk0 = gpack[va ? i0 : s0];
                int2 pk1 = gpack[vb ? i1 : s0];
                float w0 = va ? __int_as_float(pk0.y) : 0.f;
                float w1 = vb ? __int_as_float(pk1.y) : 0.f;
                bf16x8 ev0 = *(const bf16x8*)(embh + (size_t)pk0.x * 128 + l15 * 8);
                bf16x8 ev1 = *(const bf16x8*)(embh + (size_t)pk1.x * 128 + l15 * 8);
                const u32* e0p = (const u32*)&ev0;
                const u32* e1p = (const u32*)&ev1;
#pragma unroll
                for (int j = 0; j < 4; j++) {
                    accm[2 * j]     += w0 * b2f(e0p[j]) + w1 * b2f(e1p[j]);
                    accm[2 * j + 1] += w0 * b2f(e0p[j] >> 16) + w1 * b2f(e1p[j] >> 16);
                }
                c += w0 + w1;
            }
#pragma unroll
            for (int j = 0; j < 8; j++) {
                accm[j] += __shfl_xor(accm[j], 16);
                accm[j] += __shfl_xor(accm[j], 32);
            }
            c += __shfl_xor(c, 16);
            c += __shfl_xor(c, 32);
            c = c > 1.f ? c : 1.f;
            float minv = 1.f / c;
            if (quad == 0) {
                uint4 o4;
                u32* op = (u32*)&o4;
#pragma unroll
                for (int j = 0; j < 4; j++)
                    op[j] = (u32)f2b(accm[2 * j] * minv) |
                            ((u32)f2b(accm[2 * j + 1] * minv) << 16);
                *(uint4*)&sX[2][local][l15 * 8] = o4;
            }
        }
    }
    __syncthreads();

    // phase 2: MFMA epilogue. wave wid owns output d-tile [wid*16, wid*16+16).
    int d = wid * 16 + l15;
    const float* biases[3] = {b1, b2, b3};
    f32x4 res0 = {0.f, 0.f, 0.f, 0.f};
    f32x4 res1 = {0.f, 0.f, 0.f, 0.f};
    f32x4 res2 = {0.f, 0.f, 0.f, 0.f};
    f32x4 res3 = {0.f, 0.f, 0.f, 0.f};
#pragma unroll
    for (int arr = 0; arr < 3; arr++) {
        bf16x8 b[4];
#pragma unroll
        for (int ks = 0; ks < 4; ks++)
            b[ks] = *(const bf16x8*)(W123h + (size_t)arr * 16384 +
                                     (size_t)d * 128 + ks * 32 + quad * 8);
        float bias = biases[arr][d];
#pragma unroll
        for (int ms = 0; ms < 4; ms++) {
            f32x4 acc = {0.f, 0.f, 0.f, 0.f};
#pragma unroll
            for (int ks = 0; ks < 4; ks++) {
                bf16x8 a = *(const bf16x8*)&sX[arr][ms * 16 + l15][ks * 32 + quad * 8];
                acc = MFMA16x16(a, b[ks], acc);
            }
            f32x4& res = (ms == 0) ? res0 : (ms == 1) ? res1 : (ms == 2) ? res2 : res3;
#pragma unroll
            for (int r = 0; r < 4; r++)
                res[r] += tanh_fast(acc[r] + bias);
        }
    }
#pragma unroll
    for (int ms = 0; ms < 4; ms++) {
        f32x4& res = (ms == 0) ? res0 : (ms == 1) ? res1 : (ms == 2) ? res2 : res3;
#pragma unroll
        for (int r = 0; r < 4; r++) {
            int orow = nb + ms * 16 + quad * 4 + r;
            if (orow < N)
                out[(size_t)orow * 128 + d] = res[r];
        }
    }
}

extern "C" void kernel_launch(void* const* d_in, const int* in_sizes, int n_in,
                              void* d_out, int out_size, void* d_ws, size_t ws_size,
                              hipStream_t stream) {
    const float* emb     = (const float*)d_in[0];
    const int*   er_src  = (const int*)d_in[1];
    const int*   er_dst  = (const int*)d_in[2];
    const int*   ee_src  = (const int*)d_in[3];
    const int*   ee_dst  = (const int*)d_in[4];
    const float* ee_w    = (const float*)d_in[5];
    const int*   rr_src  = (const int*)d_in[6];
    const int*   rr_dst  = (const int*)d_in[7];
    const float* Wattn   = (const float*)d_in[8];
    const float* Wattn_b = (const float*)d_in[9];
    const float* w0w     = (const float*)d_in[10];
    const float* w0b     = (const float*)d_in[11];
    const float* W1      = (const float*)d_in[12];
    const float* b1      = (const float*)d_in[13];
    const float* W2      = (const float*)d_in[14];
    const float* b2      = (const float*)d_in[15];
    const float* W3      = (const float*)d_in[16];
    const float* b3      = (const float*)d_in[17];
    float* out = (float*)d_out;

    int N    = in_sizes[0] / D;
    int E_ER = in_sizes[1];
    int E_EE = in_sizes[3];
    int E_RR = in_sizes[6];
    int E_M  = E_ER + E_EE + E_RR;

    int NBK = (N + 127) >> 7;        // buckets of 128 nodes (<=1024 buckets)
    int HL  = NBK * 256;             // hist entries per list ([bucket][block], 256 blocks)

    char* ws = (char*)d_ws;
    size_t off_b = 0;
    auto alloc = [&](size_t bytes) -> void* {
        void* p = ws + off_b;
        off_b += (bytes + 255) & ~(size_t)255;
        return p;
    };
    // A (N x 256 bf16) not written until k_precompute_mfma; CSR-build scratch
    // (recM/recA/hists/scans, ~22.4 MB) is carved from it.
    u16*   embh   = (u16*)alloc((size_t)N * 128 * 2);
    u16*   A      = (u16*)alloc((size_t)N * 256 * 2);
    u16*   Wcat_h = (u16*)alloc(256 * 128 * 2);
    u16*   W123h  = (u16*)alloc(3 * 128 * 128 * 2);
    int*   off_src  = (int*)alloc((size_t)(N + 1) * 4);
    int*   off_mean = (int*)alloc((size_t)(N + 1) * 4);
    int*   bsum     = (int*)alloc(514 * 4);  // [bsumA | bsumB | 2 scratch totals]
    int*   er_lst   = (int*)alloc((size_t)E_ER * 4);
    int2*  gpack    = (int2*)alloc((size_t)E_M * 8);

    // scratch carved from A:
    char* Ab   = (char*)A;
    int2* recM = (int2*)Ab;                                  // E_M * 8
    int*  recA = (int*)(Ab + (size_t)E_M * 8);               // E_ER * 4
    int*  hist2 = (int*)(Ab + (size_t)E_M * 8 + (size_t)E_ER * 4);  // 2*HL * 4
    int*  offHA = hist2 + 2 * HL;                            // HL * 4
    int*  offHM = offHA + HL;                                // HL * 4

    int nbh = (HL + 1023) / 1024;  // <= 256

    // --- casts (independent) ---
    k_cast4<<<((N * 128 / 4) + 255) / 256, 256, 0, stream>>>(emb, embh, N * 128 / 4);
    k_cast_w<<<(81920 + 255) / 256, 256, 0, stream>>>(Wattn, W1, W2, W3, Wcat_h, W123h);

    // --- bucketed CSR build ---
    k_bhist<<<256, 256, 0, stream>>>(er_src, er_dst, ee_src, rr_src,
                                     hist2, hist2 + HL, E_ER, E_EE, E_RR, NBK);
    k_scan1_dual<<<2 * nbh, 256, 0, stream>>>(hist2, HL, offHA, offHM, bsum, nbh);
    k_scan2_dual<<<2, 256, 0, stream>>>(bsum, nbh, bsum + 512, bsum + 513);
    k_scan3b<<<(2 * HL + 255) / 256, 256, 0, stream>>>(offHA, offHM, bsum, HL);
    k_bin<<<256, 256, 0, stream>>>(er_src, er_dst, ee_src, ee_dst, rr_src, rr_dst, ee_w,
                                   offHA, offHM, recA, recM, E_ER, E_EE, E_RR, NBK);
    k_bucket<<<NBK, 256, 0, stream>>>(offHA, offHM, recA, recM,
                                      off_src, off_mean, er_lst, gpack,
                                      E_ER, E_M, N, NBK);

    // --- compute ---
    k_precompute_mfma<<<(N + 63) / 64, 256, 0, stream>>>(embh, Wcat_h, A, N);
    k_fuse<<<(N + 63) / 64, 512, 0, stream>>>(A, off_src, er_lst, off_mean, gpack,
                                              embh, Wattn_b, w0w, w0b, W123h,
                                              b1, b2, b3, out, N);
}